// Round 14
// baseline (256.624 us; speedup 1.0000x reference)
//
#include <hip/hip_runtime.h>
#include <hip/hip_bf16.h>
#include <cstddef>

// Problem constants
#define NPTS 4096
#define CCH  128
#define KNN  9
#define GRP  4
#define BB   4
// workspace layout (float offsets)
#define OFF_XT    0u          // 2097152 floats
#define OFF_XX    2097152u    // 16384
#define OFF_XHI   2113536u    // 1048576 float-slots = 2097152 bf16 (pre-swizzled)
#define OFF_IDX   3162112u    // 147456 ints
#define OFF_O     3309568u    // O: 4849664 floats. candbuf aliases 2097152 floats here —
                              // fits entirely inside the O region (no Y overlap).
#define OFF_Y     8159232u    // 2097152 float-slots; used as bf16 Y (1M slots)
#define OFF_GNP   10256384u   // 131072
#define OFF_GNA   10387456u   // 512
#define OFF_GND   10387968u   // 512
#define OFF_WP    10388480u   // 65536 (unused since R13 — fp32 Wp dropped)
#define OFF_BIASP 10454016u   // 512
#define OFF_BNSUM 10454528u   // 128
#define OFF_BNSQ  10454656u   // 128
#define OFF_BNSC  10454784u   // 128
#define OFF_BNSH  10454912u   // 128
#define OFF_WLB   10455040u   // bf16 320x128 = 40960 shorts = 20480 float-slots
#define OFF_B320  10475520u   // 320 floats (padded linear bias)
#define OFF_WPB   10475840u   // bf16 4x128x128 = 65536 shorts = 32768 float-slots

using bf16x8 = __attribute__((ext_vector_type(8))) short;
using f32x4  = __attribute__((ext_vector_type(4))) float;

// compare-exchange, descending (a keeps max) — v_max_f32/v_min_f32, parallel ILP
#define CE(a, b) { float _h = fmaxf(a, b); b = fminf(a, b); a = _h; }

// 32-CE bitonic merge (descending) of a 16-element bitonic register array
#define BMERGE16(s) \
  CE(s[0],s[8])  CE(s[1],s[9])  CE(s[2],s[10]) CE(s[3],s[11]) \
  CE(s[4],s[12]) CE(s[5],s[13]) CE(s[6],s[14]) CE(s[7],s[15]) \
  CE(s[0],s[4])  CE(s[1],s[5])  CE(s[2],s[6])  CE(s[3],s[7])  \
  CE(s[8],s[12]) CE(s[9],s[13]) CE(s[10],s[14]) CE(s[11],s[15]) \
  CE(s[0],s[2])  CE(s[1],s[3])  CE(s[4],s[6])  CE(s[5],s[7])  \
  CE(s[8],s[10]) CE(s[9],s[11]) CE(s[12],s[14]) CE(s[13],s[15]) \
  CE(s[0],s[1])  CE(s[2],s[3])  CE(s[4],s[5])  CE(s[6],s[7])  \
  CE(s[8],s[9])  CE(s[10],s[11]) CE(s[12],s[13]) CE(s[14],s[15])

// Sentinel: packed(-FLT_MAX, idx=0) = 0xFF7FF000 — finite huge-negative float,
// always below any real packed key (|key| <= O(100)); never NaN.
#define SENT_BITS 0xFF7FF000u

__device__ __forceinline__ unsigned short f2bf(float v) {
  __hip_bfloat16 h = __float2bfloat16(v);
  return *reinterpret_cast<unsigned short*>(&h);
}

// ---------------- K1: transpose [B,C,N] -> xt [B*N,C] fp32 + pre-swizzled bf16 xhi + xx ----
// xhi swizzle: 16B granule g (8 bf16) of row R stored at slot g ^ (R&15). For k_knn's
// candidate loads it makes each quad-group's 4 granule reads land in ONE 64B line per row.
__global__ void k_transpose(const float* __restrict__ x, float* __restrict__ xt,
                            __hip_bfloat16* __restrict__ xhi, float* __restrict__ xx) {
  __shared__ float t[32][33];
  int tx = threadIdx.x, ty = threadIdx.y;
  int n0 = blockIdx.x * 32, c0 = blockIdx.y * 32, b = blockIdx.z;
  float v = x[((size_t)b * CCH + c0 + ty) * NPTS + n0 + tx];
  t[ty][tx] = v;
  __syncthreads();
  float tv = t[tx][ty];
  size_t R = (size_t)b * NPTS + n0 + ty;
  int c = c0 + tx;
  xt[R * CCH + c] = tv;
  int g = c >> 3, w = c & 7;
  int sc = (((g ^ ((n0 + ty) & 15)) << 3) | w);
  xhi[R * CCH + sc] = __float2bfloat16(tv);
  if (ty == 0) {
    float s = 0.f;
    #pragma unroll
    for (int k = 0; k < 32; k++) { float u = t[k][tx]; s += u * u; }
    atomicAdd(&xx[b * NPTS + n0 + tx], s);
  }
}

// selection for one chunk: pack 8 keys (idx in low 12 mantissa bits), Batcher sort-8,
// bitonic keep-top-8 merge into the running top8.
__device__ __forceinline__ void select_chunk(int c, int wave, int quad,
                                             const f32x4 (&acc)[2][2],
                                             float (&top8)[2][8]) {
  const unsigned cbase = (unsigned)(c * 128 + wave * 32 + quad * 4);
  #pragma unroll
  for (int qt = 0; qt < 2; qt++) {
    float k[8];
    #pragma unroll
    for (int ct = 0; ct < 2; ct++)
      #pragma unroll
      for (int r = 0; r < 4; r++) {
        unsigned u = __float_as_uint(acc[ct][qt][r]);
        k[ct * 4 + r] = __uint_as_float((u & 0xFFFFF000u) |
                                        (cbase + (unsigned)(ct * 16 + r)));
      }
    // Batcher odd-even mergesort 8 (19 CE), descending
    CE(k[0],k[1]) CE(k[2],k[3]) CE(k[4],k[5]) CE(k[6],k[7])
    CE(k[0],k[2]) CE(k[1],k[3]) CE(k[4],k[6]) CE(k[5],k[7])
    CE(k[1],k[2]) CE(k[5],k[6])
    CE(k[0],k[4]) CE(k[1],k[5]) CE(k[2],k[6]) CE(k[3],k[7])
    CE(k[2],k[4]) CE(k[3],k[5])
    CE(k[1],k[2]) CE(k[3],k[4]) CE(k[5],k[6])
    // keep-top-8 of (sorted run) U (sorted chunk): bitonic first stage...
    float t[8];
    #pragma unroll
    for (int i = 0; i < 8; i++) t[i] = fmaxf(top8[qt][i], k[7 - i]);
    // ...then bitonic sort the (down-up) bitonic result, descending (12 CE)
    CE(t[0],t[4]) CE(t[1],t[5]) CE(t[2],t[6]) CE(t[3],t[7])
    CE(t[0],t[2]) CE(t[1],t[3]) CE(t[4],t[6]) CE(t[5],t[7])
    CE(t[0],t[1]) CE(t[2],t[3]) CE(t[4],t[5]) CE(t[6],t[7])
    #pragma unroll
    for (int i = 0; i < 8; i++) top8[qt][i] = t[i];
  }
}

// issue one chunk's 8 candidate-fragment loads (global_load_dwordx4, L2-served).
// aoff covers ct=0 rows; ct=1 rows are +16*128 shorts (constant pointer offset).
__device__ __forceinline__ void load_chunk(const short* __restrict__ xb,
                                           const int (&aoff)[4], int c,
                                           bf16x8 (&af)[2][4]) {
  const short* cb = xb + c * (128 * CCH);
  #pragma unroll
  for (int ks = 0; ks < 4; ks++) {
    af[0][ks] = *(const bf16x8*)(cb + aoff[ks]);
    af[1][ks] = *(const bf16x8*)(cb + 2048 + aoff[ks]);
  }
}

// ---------------- K2: MFMA Gram (bf16) + per-chunk sort-network top-8 ----------------
// 256 thr = 4 waves, 32 queries/block, 128-cand chunks; blockIdx.z halves candidates
// (grid 1024). Queries+(-xx/2) in LDS (R8); candidate reg-dbuf (R3); cross-quad shfl
// merge epilogue (R11) stores the EXACT sorted top-16 per (z,wave) partition.
__launch_bounds__(256, 4)
__global__ void k_knn(const short* __restrict__ xhi, const float* __restrict__ xx,
                      float* __restrict__ cand) {
  __shared__ short Qs[32 * 136];   // 8704 B: 32 query rows, pitch 136 shorts, un-swizzled
  __shared__ float XXs[2048];      // 8192 B: -0.5*xx for this block's 16 chunks
  const int tid = threadIdx.x;
  const int wave = tid >> 6, lane = tid & 63;
  const int quad = lane >> 4, m = lane & 15;
  const int b = blockIdx.y;
  const int q0 = blockIdx.x * 32;
  const int z = blockIdx.z;
  const int ch0 = z * 16;                 // 0 or 16
  const short* xb = xhi + (size_t)b * NPTS * CCH;
  const float* xxb = xx + (b << 12);

  // ---- stage queries (un-swizzle: global slot s holds logical granule s^(row&15)) ----
  {
    int f = tid;
    #pragma unroll
    for (int it = 0; it < 2; it++, f += 256) {
      int row = f >> 4, s = f & 15;
      bf16x8 v = *(const bf16x8*)(xb + (size_t)(q0 + row) * CCH + s * 8);
      int g = s ^ (row & 15);
      *(bf16x8*)&Qs[row * 136 + g * 8] = v;
    }
    // stage -0.5*xx for chunks ch0..ch0+15 (2048 floats)
    const float4* src4 = (const float4*)(xxb + ch0 * 128);
    float4* dst4 = (float4*)XXs;
    #pragma unroll
    for (int j = 0; j < 2; j++) {
      float4 v = src4[tid * 2 + j];
      dst4[tid * 2 + j] = make_float4(-0.5f * v.x, -0.5f * v.y, -0.5f * v.z, -0.5f * v.w);
    }
  }

  // per-lane candidate-frag offsets (ct=0 rows) within a 128-row chunk, loop-invariant
  int aoff[4];
  #pragma unroll
  for (int ks = 0; ks < 4; ks++)
    aoff[ks] = (wave * 32 + m) * CCH + (((ks * 4 + quad) ^ m) * 8);

  float top8[2][8];
  #pragma unroll
  for (int qt = 0; qt < 2; qt++)
    #pragma unroll
    for (int p = 0; p < 8; p++) top8[qt][p] = __uint_as_float(SENT_BITS);

  f32x4 acc[2][2];
  bf16x8 bufA[2][4], bufB[2][4];

  unsigned qoff = (unsigned)(m * 272 + quad * 16);
  const unsigned xbase = (unsigned)(wave * 128 + quad * 16);

  load_chunk(xb, aoff, ch0, bufA);
  __syncthreads();

  auto mfma_lds = [&](const bf16x8 (&af)[2][4], int crel) {
    unsigned xo = xbase + (unsigned)crel * 512u;
    f32x4 ci0 = *(const f32x4*)((const char*)XXs + xo);
    f32x4 ci1 = *(const f32x4*)((const char*)XXs + xo + 64);
    acc[0][0] = ci0; acc[0][1] = ci0; acc[1][0] = ci1; acc[1][1] = ci1;
    #pragma unroll
    for (int ks = 0; ks < 4; ks++) {
      bf16x8 qv0 = *(const bf16x8*)((const char*)Qs + qoff + ks * 64);
      bf16x8 qv1 = *(const bf16x8*)((const char*)Qs + qoff + 4352 + ks * 64);
      acc[0][0] = __builtin_amdgcn_mfma_f32_16x16x32_bf16(af[0][ks], qv0, acc[0][0], 0, 0, 0);
      acc[0][1] = __builtin_amdgcn_mfma_f32_16x16x32_bf16(af[0][ks], qv1, acc[0][1], 0, 0, 0);
      acc[1][0] = __builtin_amdgcn_mfma_f32_16x16x32_bf16(af[1][ks], qv0, acc[1][0], 0, 0, 0);
      acc[1][1] = __builtin_amdgcn_mfma_f32_16x16x32_bf16(af[1][ks], qv1, acc[1][1], 0, 0, 0);
    }
  };

  for (int c = ch0; c < ch0 + 16; c += 2) {
    load_chunk(xb, aoff, c + 1, bufB);
    if (c > ch0) select_chunk(c - 1, wave, quad, acc, top8);
    asm volatile("" : "+v"(qoff));
    mfma_lds(bufA, c - ch0);
    if (c + 2 < ch0 + 16) load_chunk(xb, aoff, c + 2, bufA);
    select_chunk(c, wave, quad, acc, top8);
    asm volatile("" : "+v"(qoff));
    mfma_lds(bufB, c + 1 - ch0);
  }
  select_chunk(ch0 + 15, wave, quad, acc, top8);

  // cross-quad merge -> EXACT sorted top-16 of this wave's partition; store per (z,wave)
  #pragma unroll
  for (int qt = 0; qt < 2; qt++) {
    float s[16];
    #pragma unroll
    for (int i = 0; i < 8; i++) {
      s[i] = top8[qt][i];
      s[15 - i] = __shfl_xor(top8[qt][i], 16);
    }
    BMERGE16(s)
    float t[16];
    #pragma unroll
    for (int i = 0; i < 16; i++) t[i] = fmaxf(s[i], __shfl_xor(s[15 - i], 32));
    BMERGE16(t)
    if (quad == 0) {
      int q = q0 + qt * 16 + m;
      float* dst = cand + ((size_t)((b << 12) + q) * 128 + (size_t)(z * 4 + wave) * 16);
      *(float4*)&dst[0]  = make_float4(t[0],  t[1],  t[2],  t[3]);
      *(float4*)&dst[4]  = make_float4(t[4],  t[5],  t[6],  t[7]);
      *(float4*)&dst[8]  = make_float4(t[8],  t[9],  t[10], t[11]);
      *(float4*)&dst[12] = make_float4(t[12], t[13], t[14], t[15]);
    }
  }
}

// ---------------- K2b: merge 8 sorted-16 runs -> exact top-16 -> exact fp32 re-rank ----
__launch_bounds__(256)
__global__ void k_rerank(const float* __restrict__ cand, const float* __restrict__ xt,
                         const float* __restrict__ xx, int* __restrict__ idxOut) {
  __shared__ __align__(16) float runS[4][128];
  __shared__ int selS[4][16];
  __shared__ float keyS[4][16];
  int tid = threadIdx.x, wave = tid >> 6, lane = tid & 63;
  int qg = blockIdx.x * 4 + wave;
  int b = qg >> 12;
  const float* src = cand + (size_t)qg * 128;
  if (lane < 32) *(float4*)&runS[wave][lane * 4] = *(const float4*)&src[lane * 4];
  __syncthreads();
  if (lane < 16) {
    float t = runS[wave][lane];
    #pragma unroll
    for (int r = 1; r < 8; r++) {
      t = fmaxf(t, runS[wave][r * 16 + (15 - lane)]);
      #pragma unroll
      for (int d = 8; d >= 1; d >>= 1) {
        float o = __shfl_xor(t, d);
        t = (lane & d) ? fminf(t, o) : fmaxf(t, o);
      }
    }
    selS[wave][lane] = (int)(__float_as_uint(t) & 0xFFFu);
  }
  __syncthreads();
  int cnum = lane >> 2, part = lane & 3;
  int cidx = selS[wave][cnum];
  const float* rq = xt + (size_t)qg * CCH;
  const float* rc = xt + ((size_t)(b << 12) + cidx) * CCH;
  float dot = 0.f;
  #pragma unroll
  for (int j = 0; j < 8; j++) {
    float4 a4 = *(const float4*)&rq[part * 32 + j * 4];
    float4 c4 = *(const float4*)&rc[part * 32 + j * 4];
    dot += a4.x * c4.x + a4.y * c4.y + a4.z * c4.z + a4.w * c4.w;
  }
  dot += __shfl_xor(dot, 1);
  dot += __shfl_xor(dot, 2);
  if (part == 0)
    keyS[wave][cnum] = fmaf(2.f, dot, -xx[(b << 12) + cidx]);
  __syncthreads();
  if (lane < 16) {
    float k = keyS[wave][lane]; int i = selS[wave][lane];
    int r = 0;
    #pragma unroll
    for (int f = 0; f < 16; f++) {
      float fk = keyS[wave][f]; int fi = selS[wave][f];
      r += (fk > k) || (fk == k && fi < i);
    }
    if (r < 9) idxOut[(size_t)qg * 9 + r] = i;
  }
}

// ---------------- K2c: bf16 prep for the linear weights (once, batch-independent) ----
// WLB[320][128] bf16: rows 0-127 = Wa+Wb, 128-255 = Wb, 256-291 = w_aw, 292-319 = 0.
// biasB[320]: b_lin / 0 / b_aw / 0.
__global__ void k_wlinprep(const float* __restrict__ w_lin, const float* __restrict__ b_lin,
                           const float* __restrict__ w_aw, const float* __restrict__ b_aw,
                           unsigned short* __restrict__ wlb, float* __restrict__ biasB) {
  int tid = blockIdx.x * 256 + threadIdx.x;   // grid 160 blocks x 256 = 40960
  int o = tid >> 7, c = tid & 127;
  float v;
  if (o < 128)      v = w_lin[(size_t)o * 256 + c] + w_lin[(size_t)o * 256 + 128 + c];
  else if (o < 256) v = w_lin[(size_t)(o - 128) * 256 + 128 + c];
  else if (o < 292) v = w_aw[(size_t)(o - 256) * 128 + c];
  else              v = 0.f;
  wlb[tid] = f2bf(v);
  if (tid < 320)
    biasB[tid] = (tid < 128) ? b_lin[tid] : ((tid >= 256 && tid < 292) ? b_aw[tid - 256] : 0.f);
}

// ---------------- K3: MFMA linear — O[p][0:292] = [u; v; aw] ----------------
// LDS-free: A (weights) from WLB bf16 (80 KB, L2), B (points) from pre-swizzled xhi.
// 4 waves x (16 outputs x 64 points); C layout: row(quad*4+r)=output, col(m)=point.
__launch_bounds__(256)
__global__ void k_linear(const short* __restrict__ xhi, const short* __restrict__ wlb,
                         const float* __restrict__ biasB, float* __restrict__ O) {
  const int tid = threadIdx.x;
  const int wave = tid >> 6, lane = tid & 63;
  const int quad = lane >> 4, m = lane & 15;
  const int p0 = blockIdx.x * 64;
  const int ob = blockIdx.y * 64 + wave * 16;   // wave's 16 outputs
  const short* arow = wlb + (size_t)(ob + m) * 128;
  float4 bias = *(const float4*)&biasB[ob + quad * 4];
  f32x4 acc[4];
  #pragma unroll
  for (int pt = 0; pt < 4; pt++) { acc[pt][0] = bias.x; acc[pt][1] = bias.y; acc[pt][2] = bias.z; acc[pt][3] = bias.w; }
  #pragma unroll
  for (int ks = 0; ks < 4; ks++) {
    bf16x8 a = *(const bf16x8*)(arow + (ks * 4 + quad) * 8);
    #pragma unroll
    for (int pt = 0; pt < 4; pt++) {
      int row = p0 + pt * 16 + m;
      int slot = (ks * 4 + quad) ^ m;             // xhi is pre-swizzled
      bf16x8 bfr = *(const bf16x8*)(xhi + (size_t)row * 128 + slot * 8);
      acc[pt] = __builtin_amdgcn_mfma_f32_16x16x32_bf16(a, bfr, acc[pt], 0, 0, 0);
    }
  }
  if (ob + quad * 4 < 292) {
    #pragma unroll
    for (int pt = 0; pt < 4; pt++) {
      int p = p0 + pt * 16 + m;
      *(float4*)&O[(size_t)p * 296 + ob + quad * 4] =
          make_float4(acc[pt][0], acc[pt][1], acc[pt][2], acc[pt][3]);
    }
  }
}

// ---------------- K4: per-point grouped attention, residual, GN partials ----------------
// Y written as bf16 (only consumer is the MFMA conv); GN stats stay fp32.
__launch_bounds__(256)
__global__ void k_attn(const float* __restrict__ O, const int* __restrict__ idxArr,
                       const float* __restrict__ xt, __hip_bfloat16* __restrict__ Y,
                       float* __restrict__ gnPart) {
  __shared__ __align__(16) float fF[4][1188];
  __shared__ __align__(16) float scS[4][432];
  __shared__ float awS[4][48];
  __shared__ float w9S[4][48];
  __shared__ int tI[45], tJ[45];
  int tid = threadIdx.x;
  int wave = tid >> 6, l = tid & 63;
  int pos = blockIdx.x * 4 + wave;
  int b = pos >> 12;
  if (tid == 0) {
    int p = 0;
    for (int i = 0; i < 9; i++) for (int j = i; j < 9; j++) { tI[p] = i; tJ[p] = j; p++; }
  }
  int nbr[9];
  const float* Op = O + (size_t)pos * 296;
  #pragma unroll
  for (int k = 0; k < 9; k++) nbr[k] = idxArr[(size_t)pos * 9 + k];
  float2 u = *(const float2*)(Op + 2 * l);
  float* fFw = fF[wave];
  #pragma unroll
  for (int k = 0; k < 9; k++) {
    const float* vp = O + (size_t)((b << 12) + nbr[k]) * 296 + 128;
    float2 vv = *(const float2*)(vp + 2 * l);
    *(float2*)&fFw[k * 132 + 2 * l] = make_float2(u.x - vv.x, u.y - vv.y);
  }
  __syncthreads();
  #pragma unroll
  for (int r = 0; r < 3; r++) {
    int p = r * 64 + l;
    if (p < 180) {
      int g = p / 45, q = p - g * 45;
      int i = tI[q], j = tJ[q];
      const float* fi = fFw + i * 132 + g * 32;
      const float* fj = fFw + j * 132 + g * 32;
      float s = 0.f;
      #pragma unroll
      for (int t8 = 0; t8 < 8; t8++) {
        float4 a4 = *(const float4*)(fi + 4 * t8);
        float4 b4 = *(const float4*)(fj + 4 * t8);
        s += a4.x * b4.x + a4.y * b4.y + a4.z * b4.z + a4.w * b4.w;
      }
      s *= 0.17677669529663687f; // 1/sqrt(32)
      scS[wave][(g * 9 + i) * 12 + j] = s;
      scS[wave][(g * 9 + j) * 12 + i] = s;
    }
  }
  __syncthreads();
  if (l < 36) {
    int g = l / 9, i = l - g * 9;
    float* rp = &scS[wave][(g * 9 + i) * 12];
    float mx = rp[0];
    #pragma unroll
    for (int j = 1; j < 9; j++) mx = fmaxf(mx, rp[j]);
    float e[9]; float sm = 0.f;
    #pragma unroll
    for (int j = 0; j < 9; j++) { e[j] = __expf(rp[j] - mx); sm += e[j]; }
    float inv = 1.f / sm;
    #pragma unroll
    for (int j = 0; j < 9; j++) rp[j] = e[j] * inv;
  } else if (l < 40) {
    int g = l - 36;
    float a[9]; float mx = -3.4e38f;
    #pragma unroll
    for (int k = 0; k < 9; k++) { a[k] = Op[256 + g * 9 + k]; mx = fmaxf(mx, a[k]); }
    float sm = 0.f;
    #pragma unroll
    for (int k = 0; k < 9; k++) { a[k] = __expf(a[k] - mx); sm += a[k]; }
    float inv = 1.f / sm;
    #pragma unroll
    for (int k = 0; k < 9; k++) awS[wave][g * 12 + k] = a[k] * inv;
  }
  __syncthreads();
  if (l < 36) {
    int g = l / 9, j = l - g * 9;
    float s = 0.f;
    #pragma unroll
    for (int i = 0; i < 9; i++) s += awS[wave][g * 12 + i] * scS[wave][(g * 9 + i) * 12 + j];
    w9S[wave][g * 12 + j] = s;
  }
  __syncthreads();
  int g = l >> 4;
  float w9r[9];
  #pragma unroll
  for (int j = 0; j < 9; j++) w9r[j] = w9S[wave][g * 12 + j];
  int c0 = 2 * l;
  float lf0 = 0.f, lf1 = 0.f;
  #pragma unroll
  for (int j = 0; j < 9; j++) {
    float2 f2 = *(const float2*)&fFw[j * 132 + c0];
    float e0 = f2.x > 0.f ? f2.x : __expf(f2.x) - 1.f;
    float e1 = f2.y > 0.f ? f2.y : __expf(f2.y) - 1.f;
    lf0 += w9r[j] * e0;
    lf1 += w9r[j] * e1;
  }
  float2 xv = *(const float2*)(xt + (size_t)pos * CCH + c0);
  float y0 = lf0 + xv.x, y1 = lf1 + xv.y;
  unsigned short us0 = f2bf(y0), us1 = f2bf(y1);
  unsigned upak = (unsigned)us0 | ((unsigned)us1 << 16);
  *(unsigned*)((unsigned short*)Y + (size_t)pos * CCH + c0) = upak;
  float s1 = y0 + y1, s2 = y0 * y0 + y1 * y1;
  #pragma unroll
  for (int mm = 1; mm <= 8; mm <<= 1) { s1 += __shfl_xor(s1, mm); s2 += __shfl_xor(s2, mm); }
  if ((l & 15) == 0) {
    gnPart[(size_t)pos * 8 + g * 2]     = s1;
    gnPart[(size_t)pos * 8 + g * 2 + 1] = s2;
  }
}

// ---------------- K5: GN stats -> per (b,c) affine a,d ----------------
__global__ void k_gnstats(const float* __restrict__ gnPart,
                          const float* __restrict__ gn_g, const float* __restrict__ gn_b,
                          float* __restrict__ gnA, float* __restrict__ gnD) {
  int bg = blockIdx.x; int b = bg >> 2, g = bg & 3;
  int tid = threadIdx.x;
  float s1 = 0.f, s2 = 0.f;
  for (int r = tid; r < NPTS; r += 256) {
    const float* p = gnPart + (size_t)(b * NPTS + r) * 8 + g * 2;
    s1 += p[0]; s2 += p[1];
  }
  __shared__ float r1[256], r2[256];
  r1[tid] = s1; r2[tid] = s2;
  __syncthreads();
  for (int off = 128; off > 0; off >>= 1) {
    if (tid < off) { r1[tid] += r1[tid + off]; r2[tid] += r2[tid + off]; }
    __syncthreads();
  }
  __shared__ float muS, rsS;
  if (tid == 0) {
    float mu = r1[0] * (1.f / 131072.f);
    float var = r2[0] * (1.f / 131072.f) - mu * mu;
    muS = mu; rsS = 1.f / sqrtf(var + 1e-5f);
  }
  __syncthreads();
  if (tid < 32) {
    int c = g * 32 + tid;
    float a = rsS * gn_g[c];
    gnA[b * 128 + c] = a;
    gnD[b * 128 + c] = gn_b[c] - muS * a;
  }
}

// ---------------- K5b: fold GN affine into conv weights per batch (bf16 out) ----------
__global__ void k_fold(const float* __restrict__ conv_w, const float* __restrict__ conv_b,
                       const float* __restrict__ gnA, const float* __restrict__ gnD,
                       unsigned short* __restrict__ Wpb, float* __restrict__ biasp) {
  int b = blockIdx.x; int tid = threadIdx.x;
  __shared__ float dS[128], aS[128];
  if (tid < 128) { dS[tid] = gnD[b * 128 + tid]; aS[tid] = gnA[b * 128 + tid]; }
  __syncthreads();
  for (int f = tid; f < 16384; f += 256)
    Wpb[(size_t)b * 16384 + f] = f2bf(conv_w[f] * aS[f & 127]);
  if (tid < 128) {
    float s = conv_b[tid];
    for (int c = 0; c < 128; c++) s += conv_w[tid * 128 + c] * dS[c];
    biasp[b * 128 + tid] = s;
  }
}

// ---------------- K6: MFMA conv — BN partial sums ONLY (no zpre materialization) ------
// R14: the 32MB zpre write + 32MB re-read was ~10us of traffic; recomputing the GEMM in
// k_final is cheaper (MFMA ~2us, inputs 8.1MB L2). This kernel now only produces stats.
__launch_bounds__(256)
__global__ void k_conv(const short* __restrict__ Ybf, const short* __restrict__ Wpb,
                       const float* __restrict__ biasp,
                       float* __restrict__ bnSum, float* __restrict__ bnSq) {
  const int tid = threadIdx.x;
  const int wave = tid >> 6, lane = tid & 63;
  const int quad = lane >> 4, m = lane & 15;
  const int n0 = blockIdx.x * 64, b = blockIdx.z;
  const int obase = blockIdx.y * 64 + wave * 16;
  const short* arow = Wpb + (size_t)b * 16384 + (size_t)(obase + m) * 128;
  float4 bias = *(const float4*)&biasp[b * 128 + obase + quad * 4];
  f32x4 acc[4];
  #pragma unroll
  for (int pt = 0; pt < 4; pt++) { acc[pt][0] = bias.x; acc[pt][1] = bias.y; acc[pt][2] = bias.z; acc[pt][3] = bias.w; }
  #pragma unroll
  for (int ks = 0; ks < 4; ks++) {
    bf16x8 a = *(const bf16x8*)(arow + (ks * 4 + quad) * 8);
    #pragma unroll
    for (int pt = 0; pt < 4; pt++) {
      int n = n0 + pt * 16 + m;
      bf16x8 bfr = *(const bf16x8*)(Ybf + ((size_t)((b << 12) + n)) * 128 + (ks * 4 + quad) * 8);
      acc[pt] = __builtin_amdgcn_mfma_f32_16x16x32_bf16(a, bfr, acc[pt], 0, 0, 0);
    }
  }
  float p1[4] = {0.f, 0.f, 0.f, 0.f}, p2[4] = {0.f, 0.f, 0.f, 0.f};
  #pragma unroll
  for (int pt = 0; pt < 4; pt++) {
    #pragma unroll
    for (int r = 0; r < 4; r++) {
      float z = acc[pt][r];
      p1[r] += z; p2[r] += z * z;
    }
  }
  #pragma unroll
  for (int r = 0; r < 4; r++) {
    #pragma unroll
    for (int d = 1; d <= 8; d <<= 1) { p1[r] += __shfl_xor(p1[r], d); p2[r] += __shfl_xor(p2[r], d); }
  }
  if (m == 0) {
    #pragma unroll
    for (int r = 0; r < 4; r++) {
      atomicAdd(&bnSum[obase + quad * 4 + r], p1[r]);
      atomicAdd(&bnSq[obase + quad * 4 + r], p2[r]);
    }
  }
}

// ---------------- K7a: BN finalize ----------------
__global__ void k_bnfin(const float* __restrict__ bnSum, const float* __restrict__ bnSq,
                        const float* __restrict__ bn_g, const float* __restrict__ bn_b,
                        float* __restrict__ bnScale, float* __restrict__ bnShift) {
  int o = threadIdx.x;
  float m = bnSum[o] * (1.f / 16384.f);
  float v = bnSq[o] * (1.f / 16384.f) - m * m;
  float sc = bn_g[o] / sqrtf(v + 1e-5f);
  bnScale[o] = sc;
  bnShift[o] = bn_b[o] - m * sc;
}

// ---------------- K7b: fused MFMA conv + BN affine + ReLU -> d_out ----------------
// Identical MFMA loop as k_conv (same operands, same order -> bitwise-identical z),
// then out = relu(z*scale+shift) written directly. No zpre round-trip.
__launch_bounds__(256)
__global__ void k_final(const short* __restrict__ Ybf, const short* __restrict__ Wpb,
                        const float* __restrict__ biasp, const float* __restrict__ bnScale,
                        const float* __restrict__ bnShift, float* __restrict__ out) {
  const int tid = threadIdx.x;
  const int wave = tid >> 6, lane = tid & 63;
  const int quad = lane >> 4, m = lane & 15;
  const int n0 = blockIdx.x * 64, b = blockIdx.z;
  const int obase = blockIdx.y * 64 + wave * 16;
  const short* arow = Wpb + (size_t)b * 16384 + (size_t)(obase + m) * 128;
  float4 bias = *(const float4*)&biasp[b * 128 + obase + quad * 4];
  f32x4 acc[4];
  #pragma unroll
  for (int pt = 0; pt < 4; pt++) { acc[pt][0] = bias.x; acc[pt][1] = bias.y; acc[pt][2] = bias.z; acc[pt][3] = bias.w; }
  #pragma unroll
  for (int ks = 0; ks < 4; ks++) {
    bf16x8 a = *(const bf16x8*)(arow + (ks * 4 + quad) * 8);
    #pragma unroll
    for (int pt = 0; pt < 4; pt++) {
      int n = n0 + pt * 16 + m;
      bf16x8 bfr = *(const bf16x8*)(Ybf + ((size_t)((b << 12) + n)) * 128 + (ks * 4 + quad) * 8);
      acc[pt] = __builtin_amdgcn_mfma_f32_16x16x32_bf16(a, bfr, acc[pt], 0, 0, 0);
    }
  }
  float4 sc4 = *(const float4*)&bnScale[obase + quad * 4];
  float4 sh4 = *(const float4*)&bnShift[obase + quad * 4];
  float sc[4] = {sc4.x, sc4.y, sc4.z, sc4.w};
  float sh[4] = {sh4.x, sh4.y, sh4.z, sh4.w};
  #pragma unroll
  for (int pt = 0; pt < 4; pt++) {
    int n = n0 + pt * 16 + m;
    #pragma unroll
    for (int r = 0; r < 4; r++) {
      float v = fmaxf(fmaf(acc[pt][r], sc[r], sh[r]), 0.f);
      out[(((size_t)((b << 7) + obase + quad * 4 + r)) << 12) + n] = v;
    }
  }
}

extern "C" void kernel_launch(void* const* d_in, const int* in_sizes, int n_in,
                              void* d_out, int out_size, void* d_ws, size_t ws_size,
                              hipStream_t stream) {
  const float* features = (const float*)d_in[0];
  const float* w_lin  = (const float*)d_in[1];
  const float* b_lin  = (const float*)d_in[2];
  const float* w_aw   = (const float*)d_in[3];
  const float* b_aw   = (const float*)d_in[4];
  const float* gn_g   = (const float*)d_in[5];
  const float* gn_b   = (const float*)d_in[6];
  const float* conv_w = (const float*)d_in[7];
  const float* conv_b = (const float*)d_in[8];
  const float* bn_g   = (const float*)d_in[9];
  const float* bn_b   = (const float*)d_in[10];

  float* ws    = (float*)d_ws;
  float* xt    = ws + OFF_XT;
  float* xxp   = ws + OFF_XX;
  __hip_bfloat16* xhip = (__hip_bfloat16*)(ws + OFF_XHI);
  int*   idxp  = (int*)(ws + OFF_IDX);
  float* Op    = ws + OFF_O;
  float* candp = ws + OFF_O;   // alias: cand (2.1M floats) dead before k_linear writes O
  __hip_bfloat16* Ybf = (__hip_bfloat16*)(ws + OFF_Y);
  float* gnp   = ws + OFF_GNP;
  float* gnA   = ws + OFF_GNA;
  float* gnD   = ws + OFF_GND;
  float* biasp = ws + OFF_BIASP;
  float* bnSum = ws + OFF_BNSUM;
  float* bnSq  = ws + OFF_BNSQ;
  float* bnSc  = ws + OFF_BNSC;
  float* bnSh  = ws + OFF_BNSH;
  unsigned short* wlbp = (unsigned short*)(ws + OFF_WLB);
  float* biasB = ws + OFF_B320;
  unsigned short* wpbp = (unsigned short*)(ws + OFF_WPB);

  hipMemsetAsync(xxp, 0, NPTS * BB * sizeof(float), stream);
  hipMemsetAsync(bnSum, 0, 256 * sizeof(float), stream); // bnSum + bnSq contiguous

  k_transpose<<<dim3(128, 4, 4), dim3(32, 32), 0, stream>>>(features, xt, xhip, xxp);
  k_wlinprep<<<160, 256, 0, stream>>>(w_lin, b_lin, w_aw, b_aw, wlbp, biasB);
  k_knn<<<dim3(128, 4, 2), 256, 0, stream>>>((const short*)xhip, xxp, candp);
  k_rerank<<<4096, 256, 0, stream>>>(candp, xt, xxp, idxp);
  k_linear<<<dim3(256, 5), 256, 0, stream>>>((const short*)xhip, (const short*)wlbp, biasB, Op);
  k_attn<<<4096, 256, 0, stream>>>(Op, idxp, xt, Ybf, gnp);
  k_gnstats<<<16, 256, 0, stream>>>(gnp, gn_g, gn_b, gnA, gnD);
  k_fold<<<4, 256, 0, stream>>>(conv_w, conv_b, gnA, gnD, wpbp, biasp);
  k_conv<<<dim3(64, 2, 4), 256, 0, stream>>>((const short*)Ybf, (const short*)wpbp, biasp,
                                             bnSum, bnSq);
  k_bnfin<<<1, 128, 0, stream>>>(bnSum, bnSq, bn_g, bn_b, bnSc, bnSh);
  k_final<<<dim3(64, 2, 4), 256, 0, stream>>>((const short*)Ybf, (const short*)wpbp, biasp,
                                              bnSc, bnSh, (float*)d_out);
}

// Round 16
// 252.704 us; speedup vs baseline: 1.0155x; 1.0155x over previous
//
#include <hip/hip_runtime.h>
#include <hip/hip_bf16.h>
#include <cstddef>

// Problem constants
#define NPTS 4096
#define CCH  128
#define KNN  9
#define GRP  4
#define BB   4
// workspace layout (float offsets)
#define OFF_XT    0u          // 2097152 floats (reused as zpre after k_attn)
#define OFF_XX    2097152u    // 16384
#define OFF_XHI   2113536u    // 1048576 float-slots = 2097152 bf16 (pre-swizzled)
#define OFF_IDX   3162112u    // 147456 ints
#define OFF_O     3309568u    // O: 16384 x 232 = 3801088 floats (u fp32 | v bf16 | aw fp32).
                              // candbuf aliases 2097152 floats here — fits inside O.
#define OFF_Y     8159232u    // 2097152 float-slots; used as bf16 Y (1M slots)
#define OFF_GNP   10256384u   // 131072
#define OFF_GNA   10387456u   // 512
#define OFF_GND   10387968u   // 512
#define OFF_BIASP 10454016u   // 512
#define OFF_BNSUM 10454528u   // 128
#define OFF_BNSQ  10454656u   // 128
#define OFF_BNSC  10454784u   // 128
#define OFF_BNSH  10454912u   // 128
#define OFF_WLB   10455040u   // bf16 320x128 = 40960 shorts = 20480 float-slots
#define OFF_B320  10475520u   // 320 floats (padded linear bias)
#define OFF_WPB   10475840u   // bf16 4x128x128 = 65536 shorts = 32768 float-slots

#define OPITCH 232            // O row pitch in float-slots

using bf16x8 = __attribute__((ext_vector_type(8))) short;
using f32x4  = __attribute__((ext_vector_type(4))) float;

// compare-exchange, descending (a keeps max) — v_max_f32/v_min_f32, parallel ILP
#define CE(a, b) { float _h = fmaxf(a, b); b = fminf(a, b); a = _h; }

// 32-CE bitonic merge (descending) of a 16-element bitonic register array
#define BMERGE16(s) \
  CE(s[0],s[8])  CE(s[1],s[9])  CE(s[2],s[10]) CE(s[3],s[11]) \
  CE(s[4],s[12]) CE(s[5],s[13]) CE(s[6],s[14]) CE(s[7],s[15]) \
  CE(s[0],s[4])  CE(s[1],s[5])  CE(s[2],s[6])  CE(s[3],s[7])  \
  CE(s[8],s[12]) CE(s[9],s[13]) CE(s[10],s[14]) CE(s[11],s[15]) \
  CE(s[0],s[2])  CE(s[1],s[3])  CE(s[4],s[6])  CE(s[5],s[7])  \
  CE(s[8],s[10]) CE(s[9],s[11]) CE(s[12],s[14]) CE(s[13],s[15]) \
  CE(s[0],s[1])  CE(s[2],s[3])  CE(s[4],s[5])  CE(s[6],s[7])  \
  CE(s[8],s[9])  CE(s[10],s[11]) CE(s[12],s[13]) CE(s[14],s[15])

// Sentinel: packed(-FLT_MAX, idx=0) = 0xFF7FF000 — finite huge-negative float,
// always below any real packed key (|key| <= O(100)); never NaN.
#define SENT_BITS 0xFF7FF000u

__device__ __forceinline__ unsigned short f2bf(float v) {
  __hip_bfloat16 h = __float2bfloat16(v);
  return *reinterpret_cast<unsigned short*>(&h);
}

// ---------------- K1: transpose [B,C,N] -> xt [B*N,C] fp32 + pre-swizzled bf16 xhi + xx ----
// xhi swizzle: 16B granule g (8 bf16) of row R stored at slot g ^ (R&15). For k_knn's
// candidate loads it makes each quad-group's 4 granule reads land in ONE 64B line per row.
__global__ void k_transpose(const float* __restrict__ x, float* __restrict__ xt,
                            __hip_bfloat16* __restrict__ xhi, float* __restrict__ xx) {
  __shared__ float t[32][33];
  int tx = threadIdx.x, ty = threadIdx.y;
  int n0 = blockIdx.x * 32, c0 = blockIdx.y * 32, b = blockIdx.z;
  float v = x[((size_t)b * CCH + c0 + ty) * NPTS + n0 + tx];
  t[ty][tx] = v;
  __syncthreads();
  float tv = t[tx][ty];
  size_t R = (size_t)b * NPTS + n0 + ty;
  int c = c0 + tx;
  xt[R * CCH + c] = tv;
  int g = c >> 3, w = c & 7;
  int sc = (((g ^ ((n0 + ty) & 15)) << 3) | w);
  xhi[R * CCH + sc] = __float2bfloat16(tv);
  if (ty == 0) {
    float s = 0.f;
    #pragma unroll
    for (int k = 0; k < 32; k++) { float u = t[k][tx]; s += u * u; }
    atomicAdd(&xx[b * NPTS + n0 + tx], s);
  }
}

// selection for one chunk: pack 8 keys (idx in low 12 mantissa bits), Batcher sort-8,
// bitonic keep-top-8 merge into the running top8.
__device__ __forceinline__ void select_chunk(int c, int wave, int quad,
                                             const f32x4 (&acc)[2][2],
                                             float (&top8)[2][8]) {
  const unsigned cbase = (unsigned)(c * 128 + wave * 32 + quad * 4);
  #pragma unroll
  for (int qt = 0; qt < 2; qt++) {
    float k[8];
    #pragma unroll
    for (int ct = 0; ct < 2; ct++)
      #pragma unroll
      for (int r = 0; r < 4; r++) {
        unsigned u = __float_as_uint(acc[ct][qt][r]);
        k[ct * 4 + r] = __uint_as_float((u & 0xFFFFF000u) |
                                        (cbase + (unsigned)(ct * 16 + r)));
      }
    // Batcher odd-even mergesort 8 (19 CE), descending
    CE(k[0],k[1]) CE(k[2],k[3]) CE(k[4],k[5]) CE(k[6],k[7])
    CE(k[0],k[2]) CE(k[1],k[3]) CE(k[4],k[6]) CE(k[5],k[7])
    CE(k[1],k[2]) CE(k[5],k[6])
    CE(k[0],k[4]) CE(k[1],k[5]) CE(k[2],k[6]) CE(k[3],k[7])
    CE(k[2],k[4]) CE(k[3],k[5])
    CE(k[1],k[2]) CE(k[3],k[4]) CE(k[5],k[6])
    // keep-top-8 of (sorted run) U (sorted chunk): bitonic first stage...
    float t[8];
    #pragma unroll
    for (int i = 0; i < 8; i++) t[i] = fmaxf(top8[qt][i], k[7 - i]);
    // ...then bitonic sort the (down-up) bitonic result, descending (12 CE)
    CE(t[0],t[4]) CE(t[1],t[5]) CE(t[2],t[6]) CE(t[3],t[7])
    CE(t[0],t[2]) CE(t[1],t[3]) CE(t[4],t[6]) CE(t[5],t[7])
    CE(t[0],t[1]) CE(t[2],t[3]) CE(t[4],t[5]) CE(t[6],t[7])
    #pragma unroll
    for (int i = 0; i < 8; i++) top8[qt][i] = t[i];
  }
}

// issue one chunk's 8 candidate-fragment loads (global_load_dwordx4, L2-served).
// aoff covers ct=0 rows; ct=1 rows are +16*128 shorts (constant pointer offset).
__device__ __forceinline__ void load_chunk(const short* __restrict__ xb,
                                           const int (&aoff)[4], int c,
                                           bf16x8 (&af)[2][4]) {
  const short* cb = xb + c * (128 * CCH);
  #pragma unroll
  for (int ks = 0; ks < 4; ks++) {
    af[0][ks] = *(const bf16x8*)(cb + aoff[ks]);
    af[1][ks] = *(const bf16x8*)(cb + 2048 + aoff[ks]);
  }
}

// ---------------- K2: MFMA Gram (bf16) + per-chunk sort-network top-8 ----------------
// 256 thr = 4 waves, 32 queries/block, 128-cand chunks; blockIdx.z halves candidates
// (grid 1024). Queries+(-xx/2) in LDS (R8); candidate reg-dbuf (R3); cross-quad shfl
// merge epilogue (R11) stores the EXACT sorted top-16 per (z,wave) partition.
__launch_bounds__(256, 4)
__global__ void k_knn(const short* __restrict__ xhi, const float* __restrict__ xx,
                      float* __restrict__ cand) {
  __shared__ short Qs[32 * 136];   // 8704 B: 32 query rows, pitch 136 shorts, un-swizzled
  __shared__ float XXs[2048];      // 8192 B: -0.5*xx for this block's 16 chunks
  const int tid = threadIdx.x;
  const int wave = tid >> 6, lane = tid & 63;
  const int quad = lane >> 4, m = lane & 15;
  const int b = blockIdx.y;
  const int q0 = blockIdx.x * 32;
  const int z = blockIdx.z;
  const int ch0 = z * 16;                 // 0 or 16
  const short* xb = xhi + (size_t)b * NPTS * CCH;
  const float* xxb = xx + (b << 12);

  // ---- stage queries (un-swizzle: global slot s holds logical granule s^(row&15)) ----
  {
    int f = tid;
    #pragma unroll
    for (int it = 0; it < 2; it++, f += 256) {
      int row = f >> 4, s = f & 15;
      bf16x8 v = *(const bf16x8*)(xb + (size_t)(q0 + row) * CCH + s * 8);
      int g = s ^ (row & 15);
      *(bf16x8*)&Qs[row * 136 + g * 8] = v;
    }
    // stage -0.5*xx for chunks ch0..ch0+15 (2048 floats)
    const float4* src4 = (const float4*)(xxb + ch0 * 128);
    float4* dst4 = (float4*)XXs;
    #pragma unroll
    for (int j = 0; j < 2; j++) {
      float4 v = src4[tid * 2 + j];
      dst4[tid * 2 + j] = make_float4(-0.5f * v.x, -0.5f * v.y, -0.5f * v.z, -0.5f * v.w);
    }
  }

  // per-lane candidate-frag offsets (ct=0 rows) within a 128-row chunk, loop-invariant
  int aoff[4];
  #pragma unroll
  for (int ks = 0; ks < 4; ks++)
    aoff[ks] = (wave * 32 + m) * CCH + (((ks * 4 + quad) ^ m) * 8);

  float top8[2][8];
  #pragma unroll
  for (int qt = 0; qt < 2; qt++)
    #pragma unroll
    for (int p = 0; p < 8; p++) top8[qt][p] = __uint_as_float(SENT_BITS);

  f32x4 acc[2][2];
  bf16x8 bufA[2][4], bufB[2][4];

  unsigned qoff = (unsigned)(m * 272 + quad * 16);
  const unsigned xbase = (unsigned)(wave * 128 + quad * 16);

  load_chunk(xb, aoff, ch0, bufA);
  __syncthreads();

  auto mfma_lds = [&](const bf16x8 (&af)[2][4], int crel) {
    unsigned xo = xbase + (unsigned)crel * 512u;
    f32x4 ci0 = *(const f32x4*)((const char*)XXs + xo);
    f32x4 ci1 = *(const f32x4*)((const char*)XXs + xo + 64);
    acc[0][0] = ci0; acc[0][1] = ci0; acc[1][0] = ci1; acc[1][1] = ci1;
    #pragma unroll
    for (int ks = 0; ks < 4; ks++) {
      bf16x8 qv0 = *(const bf16x8*)((const char*)Qs + qoff + ks * 64);
      bf16x8 qv1 = *(const bf16x8*)((const char*)Qs + qoff + 4352 + ks * 64);
      acc[0][0] = __builtin_amdgcn_mfma_f32_16x16x32_bf16(af[0][ks], qv0, acc[0][0], 0, 0, 0);
      acc[0][1] = __builtin_amdgcn_mfma_f32_16x16x32_bf16(af[0][ks], qv1, acc[0][1], 0, 0, 0);
      acc[1][0] = __builtin_amdgcn_mfma_f32_16x16x32_bf16(af[1][ks], qv0, acc[1][0], 0, 0, 0);
      acc[1][1] = __builtin_amdgcn_mfma_f32_16x16x32_bf16(af[1][ks], qv1, acc[1][1], 0, 0, 0);
    }
  };

  for (int c = ch0; c < ch0 + 16; c += 2) {
    load_chunk(xb, aoff, c + 1, bufB);
    if (c > ch0) select_chunk(c - 1, wave, quad, acc, top8);
    asm volatile("" : "+v"(qoff));
    mfma_lds(bufA, c - ch0);
    if (c + 2 < ch0 + 16) load_chunk(xb, aoff, c + 2, bufA);
    select_chunk(c, wave, quad, acc, top8);
    asm volatile("" : "+v"(qoff));
    mfma_lds(bufB, c + 1 - ch0);
  }
  select_chunk(ch0 + 15, wave, quad, acc, top8);

  // cross-quad merge -> EXACT sorted top-16 of this wave's partition; store per (z,wave)
  #pragma unroll
  for (int qt = 0; qt < 2; qt++) {
    float s[16];
    #pragma unroll
    for (int i = 0; i < 8; i++) {
      s[i] = top8[qt][i];
      s[15 - i] = __shfl_xor(top8[qt][i], 16);
    }
    BMERGE16(s)
    float t[16];
    #pragma unroll
    for (int i = 0; i < 16; i++) t[i] = fmaxf(s[i], __shfl_xor(s[15 - i], 32));
    BMERGE16(t)
    if (quad == 0) {
      int q = q0 + qt * 16 + m;
      float* dst = cand + ((size_t)((b << 12) + q) * 128 + (size_t)(z * 4 + wave) * 16);
      *(float4*)&dst[0]  = make_float4(t[0],  t[1],  t[2],  t[3]);
      *(float4*)&dst[4]  = make_float4(t[4],  t[5],  t[6],  t[7]);
      *(float4*)&dst[8]  = make_float4(t[8],  t[9],  t[10], t[11]);
      *(float4*)&dst[12] = make_float4(t[12], t[13], t[14], t[15]);
    }
  }
}

// ---------------- K2b: merge 8 sorted-16 runs -> exact top-16 -> exact fp32 re-rank ----
__launch_bounds__(256)
__global__ void k_rerank(const float* __restrict__ cand, const float* __restrict__ xt,
                         const float* __restrict__ xx, int* __restrict__ idxOut) {
  __shared__ __align__(16) float runS[4][128];
  __shared__ int selS[4][16];
  __shared__ float keyS[4][16];
  int tid = threadIdx.x, wave = tid >> 6, lane = tid & 63;
  int qg = blockIdx.x * 4 + wave;
  int b = qg >> 12;
  const float* src = cand + (size_t)qg * 128;
  if (lane < 32) *(float4*)&runS[wave][lane * 4] = *(const float4*)&src[lane * 4];
  __syncthreads();
  if (lane < 16) {
    float t = runS[wave][lane];
    #pragma unroll
    for (int r = 1; r < 8; r++) {
      t = fmaxf(t, runS[wave][r * 16 + (15 - lane)]);
      #pragma unroll
      for (int d = 8; d >= 1; d >>= 1) {
        float o = __shfl_xor(t, d);
        t = (lane & d) ? fminf(t, o) : fmaxf(t, o);
      }
    }
    selS[wave][lane] = (int)(__float_as_uint(t) & 0xFFFu);
  }
  __syncthreads();
  int cnum = lane >> 2, part = lane & 3;
  int cidx = selS[wave][cnum];
  const float* rq = xt + (size_t)qg * CCH;
  const float* rc = xt + ((size_t)(b << 12) + cidx) * CCH;
  float dot = 0.f;
  #pragma unroll
  for (int j = 0; j < 8; j++) {
    float4 a4 = *(const float4*)&rq[part * 32 + j * 4];
    float4 c4 = *(const float4*)&rc[part * 32 + j * 4];
    dot += a4.x * c4.x + a4.y * c4.y + a4.z * c4.z + a4.w * c4.w;
  }
  dot += __shfl_xor(dot, 1);
  dot += __shfl_xor(dot, 2);
  if (part == 0)
    keyS[wave][cnum] = fmaf(2.f, dot, -xx[(b << 12) + cidx]);
  __syncthreads();
  if (lane < 16) {
    float k = keyS[wave][lane]; int i = selS[wave][lane];
    int r = 0;
    #pragma unroll
    for (int f = 0; f < 16; f++) {
      float fk = keyS[wave][f]; int fi = selS[wave][f];
      r += (fk > k) || (fk == k && fi < i);
    }
    if (r < 9) idxOut[(size_t)qg * 9 + r] = i;
  }
}

// ---------------- K2c: bf16 prep for the linear weights (once, batch-independent) ----
// WLB[320][128] bf16: rows 0-127 = Wa+Wb, 128-255 = Wb, 256-291 = w_aw, 292-319 = 0.
// biasB[320]: b_lin / 0 / b_aw / 0.
__global__ void k_wlinprep(const float* __restrict__ w_lin, const float* __restrict__ b_lin,
                           const float* __restrict__ w_aw, const float* __restrict__ b_aw,
                           unsigned short* __restrict__ wlb, float* __restrict__ biasB) {
  int tid = blockIdx.x * 256 + threadIdx.x;   // grid 160 blocks x 256 = 40960
  int o = tid >> 7, c = tid & 127;
  float v;
  if (o < 128)      v = w_lin[(size_t)o * 256 + c] + w_lin[(size_t)o * 256 + 128 + c];
  else if (o < 256) v = w_lin[(size_t)(o - 128) * 256 + 128 + c];
  else if (o < 292) v = w_aw[(size_t)(o - 256) * 128 + c];
  else              v = 0.f;
  wlb[tid] = f2bf(v);
  if (tid < 320)
    biasB[tid] = (tid < 128) ? b_lin[tid] : ((tid >= 256 && tid < 292) ? b_aw[tid - 256] : 0.f);
}

// ---------------- K3: MFMA linear — O[p] = [u fp32 | v bf16 | aw fp32], pitch 232 ------
// LDS-free: A (weights) from WLB bf16 (80 KB, L2), B (points) from pre-swizzled xhi.
// 4 waves x (16 outputs x 64 points). v quadrant (o in [128,256)) stored as bf16 at
// float-slot 128 (R15: halves k_attn's 75MB scattered v-gather).
__launch_bounds__(256)
__global__ void k_linear(const short* __restrict__ xhi, const short* __restrict__ wlb,
                         const float* __restrict__ biasB, float* __restrict__ O) {
  const int tid = threadIdx.x;
  const int wave = tid >> 6, lane = tid & 63;
  const int quad = lane >> 4, m = lane & 15;
  const int p0 = blockIdx.x * 64;
  const int ob = blockIdx.y * 64 + wave * 16;   // wave's 16 outputs
  const short* arow = wlb + (size_t)(ob + m) * 128;
  float4 bias = *(const float4*)&biasB[ob + quad * 4];
  f32x4 acc[4];
  #pragma unroll
  for (int pt = 0; pt < 4; pt++) { acc[pt][0] = bias.x; acc[pt][1] = bias.y; acc[pt][2] = bias.z; acc[pt][3] = bias.w; }
  #pragma unroll
  for (int ks = 0; ks < 4; ks++) {
    bf16x8 a = *(const bf16x8*)(arow + (ks * 4 + quad) * 8);
    #pragma unroll
    for (int pt = 0; pt < 4; pt++) {
      int row = p0 + pt * 16 + m;
      int slot = (ks * 4 + quad) ^ m;             // xhi is pre-swizzled
      bf16x8 bfr = *(const bf16x8*)(xhi + (size_t)row * 128 + slot * 8);
      acc[pt] = __builtin_amdgcn_mfma_f32_16x16x32_bf16(a, bfr, acc[pt], 0, 0, 0);
    }
  }
  int o4 = ob + quad * 4;     // wave-uniform quadrant: ob multiple of 16
  if (ob < 128) {
    #pragma unroll
    for (int pt = 0; pt < 4; pt++) {
      int p = p0 + pt * 16 + m;
      *(float4*)&O[(size_t)p * OPITCH + o4] =
          make_float4(acc[pt][0], acc[pt][1], acc[pt][2], acc[pt][3]);
    }
  } else if (ob < 256) {
    #pragma unroll
    for (int pt = 0; pt < 4; pt++) {
      int p = p0 + pt * 16 + m;
      unsigned short* vd = (unsigned short*)(O + (size_t)p * OPITCH + 128) + (o4 - 128);
      uint2 pk;
      pk.x = (unsigned)f2bf(acc[pt][0]) | ((unsigned)f2bf(acc[pt][1]) << 16);
      pk.y = (unsigned)f2bf(acc[pt][2]) | ((unsigned)f2bf(acc[pt][3]) << 16);
      *(uint2*)vd = pk;
    }
  } else if (o4 < 292) {
    #pragma unroll
    for (int pt = 0; pt < 4; pt++) {
      int p = p0 + pt * 16 + m;
      *(float4*)&O[(size_t)p * OPITCH + 192 + (o4 - 256)] =
          make_float4(acc[pt][0], acc[pt][1], acc[pt][2], acc[pt][3]);
    }
  }
}

// ---------------- K4: per-point grouped attention, residual, GN partials ----------------
// v gathered as bf16 (halved scattered traffic); edge math stays fp32 in LDS.
__launch_bounds__(256)
__global__ void k_attn(const float* __restrict__ O, const int* __restrict__ idxArr,
                       const float* __restrict__ xt, __hip_bfloat16* __restrict__ Y,
                       float* __restrict__ gnPart) {
  __shared__ __align__(16) float fF[4][1188];
  __shared__ __align__(16) float scS[4][432];
  __shared__ float awS[4][48];
  __shared__ float w9S[4][48];
  __shared__ int tI[45], tJ[45];
  int tid = threadIdx.x;
  int wave = tid >> 6, l = tid & 63;
  int pos = blockIdx.x * 4 + wave;
  int b = pos >> 12;
  if (tid == 0) {
    int p = 0;
    for (int i = 0; i < 9; i++) for (int j = i; j < 9; j++) { tI[p] = i; tJ[p] = j; p++; }
  }
  int nbr[9];
  const float* Op = O + (size_t)pos * OPITCH;
  #pragma unroll
  for (int k = 0; k < 9; k++) nbr[k] = idxArr[(size_t)pos * 9 + k];
  float2 u = *(const float2*)(Op + 2 * l);
  float* fFw = fF[wave];
  #pragma unroll
  for (int k = 0; k < 9; k++) {
    const unsigned short* vp =
        (const unsigned short*)(O + (size_t)((b << 12) + nbr[k]) * OPITCH + 128);
    unsigned pv = *(const unsigned*)(vp + 2 * l);
    float v0 = __uint_as_float((pv & 0xFFFFu) << 16);
    float v1 = __uint_as_float(pv & 0xFFFF0000u);
    *(float2*)&fFw[k * 132 + 2 * l] = make_float2(u.x - v0, u.y - v1);
  }
  __syncthreads();
  #pragma unroll
  for (int r = 0; r < 3; r++) {
    int p = r * 64 + l;
    if (p < 180) {
      int g = p / 45, q = p - g * 45;
      int i = tI[q], j = tJ[q];
      const float* fi = fFw + i * 132 + g * 32;
      const float* fj = fFw + j * 132 + g * 32;
      float s = 0.f;
      #pragma unroll
      for (int t8 = 0; t8 < 8; t8++) {
        float4 a4 = *(const float4*)(fi + 4 * t8);
        float4 b4 = *(const float4*)(fj + 4 * t8);
        s += a4.x * b4.x + a4.y * b4.y + a4.z * b4.z + a4.w * b4.w;
      }
      s *= 0.17677669529663687f; // 1/sqrt(32)
      scS[wave][(g * 9 + i) * 12 + j] = s;
      scS[wave][(g * 9 + j) * 12 + i] = s;
    }
  }
  __syncthreads();
  if (l < 36) {
    int g = l / 9, i = l - g * 9;
    float* rp = &scS[wave][(g * 9 + i) * 12];
    float mx = rp[0];
    #pragma unroll
    for (int j = 1; j < 9; j++) mx = fmaxf(mx, rp[j]);
    float e[9]; float sm = 0.f;
    #pragma unroll
    for (int j = 0; j < 9; j++) { e[j] = __expf(rp[j] - mx); sm += e[j]; }
    float inv = 1.f / sm;
    #pragma unroll
    for (int j = 0; j < 9; j++) rp[j] = e[j] * inv;
  } else if (l < 40) {
    int g = l - 36;
    float a[9]; float mx = -3.4e38f;
    #pragma unroll
    for (int k = 0; k < 9; k++) { a[k] = Op[192 + g * 9 + k]; mx = fmaxf(mx, a[k]); }
    float sm = 0.f;
    #pragma unroll
    for (int k = 0; k < 9; k++) { a[k] = __expf(a[k] - mx); sm += a[k]; }
    float inv = 1.f / sm;
    #pragma unroll
    for (int k = 0; k < 9; k++) awS[wave][g * 12 + k] = a[k] * inv;
  }
  __syncthreads();
  if (l < 36) {
    int g = l / 9, j = l - g * 9;
    float s = 0.f;
    #pragma unroll
    for (int i = 0; i < 9; i++) s += awS[wave][g * 12 + i] * scS[wave][(g * 9 + i) * 12 + j];
    w9S[wave][g * 12 + j] = s;
  }
  __syncthreads();
  int g = l >> 4;
  float w9r[9];
  #pragma unroll
  for (int j = 0; j < 9; j++) w9r[j] = w9S[wave][g * 12 + j];
  int c0 = 2 * l;
  float lf0 = 0.f, lf1 = 0.f;
  #pragma unroll
  for (int j = 0; j < 9; j++) {
    float2 f2 = *(const float2*)&fFw[j * 132 + c0];
    float e0 = f2.x > 0.f ? f2.x : __expf(f2.x) - 1.f;
    float e1 = f2.y > 0.f ? f2.y : __expf(f2.y) - 1.f;
    lf0 += w9r[j] * e0;
    lf1 += w9r[j] * e1;
  }
  float2 xv = *(const float2*)(xt + (size_t)pos * CCH + c0);
  float y0 = lf0 + xv.x, y1 = lf1 + xv.y;
  unsigned short us0 = f2bf(y0), us1 = f2bf(y1);
  unsigned upak = (unsigned)us0 | ((unsigned)us1 << 16);
  *(unsigned*)((unsigned short*)Y + (size_t)pos * CCH + c0) = upak;
  float s1 = y0 + y1, s2 = y0 * y0 + y1 * y1;
  #pragma unroll
  for (int mm = 1; mm <= 8; mm <<= 1) { s1 += __shfl_xor(s1, mm); s2 += __shfl_xor(s2, mm); }
  if ((l & 15) == 0) {
    gnPart[(size_t)pos * 8 + g * 2]     = s1;
    gnPart[(size_t)pos * 8 + g * 2 + 1] = s2;
  }
}

// ---------------- K5: GN stats -> per (b,c) affine a,d ----------------
__global__ void k_gnstats(const float* __restrict__ gnPart,
                          const float* __restrict__ gn_g, const float* __restrict__ gn_b,
                          float* __restrict__ gnA, float* __restrict__ gnD) {
  int bg = blockIdx.x; int b = bg >> 2, g = bg & 3;
  int tid = threadIdx.x;
  float s1 = 0.f, s2 = 0.f;
  for (int r = tid; r < NPTS; r += 256) {
    const float* p = gnPart + (size_t)(b * NPTS + r) * 8 + g * 2;
    s1 += p[0]; s2 += p[1];
  }
  __shared__ float r1[256], r2[256];
  r1[tid] = s1; r2[tid] = s2;
  __syncthreads();
  for (int off = 128; off > 0; off >>= 1) {
    if (tid < off) { r1[tid] += r1[tid + off]; r2[tid] += r2[tid + off]; }
    __syncthreads();
  }
  __shared__ float muS, rsS;
  if (tid == 0) {
    float mu = r1[0] * (1.f / 131072.f);
    float var = r2[0] * (1.f / 131072.f) - mu * mu;
    muS = mu; rsS = 1.f / sqrtf(var + 1e-5f);
  }
  __syncthreads();
  if (tid < 32) {
    int c = g * 32 + tid;
    float a = rsS * gn_g[c];
    gnA[b * 128 + c] = a;
    gnD[b * 128 + c] = gn_b[c] - muS * a;
  }
}

// ---------------- K5b: fold GN affine into conv weights per batch (bf16 out) ----------
__global__ void k_fold(const float* __restrict__ conv_w, const float* __restrict__ conv_b,
                       const float* __restrict__ gnA, const float* __restrict__ gnD,
                       unsigned short* __restrict__ Wpb, float* __restrict__ biasp) {
  int b = blockIdx.x; int tid = threadIdx.x;
  __shared__ float dS[128], aS[128];
  if (tid < 128) { dS[tid] = gnD[b * 128 + tid]; aS[tid] = gnA[b * 128 + tid]; }
  __syncthreads();
  for (int f = tid; f < 16384; f += 256)
    Wpb[(size_t)b * 16384 + f] = f2bf(conv_w[f] * aS[f & 127]);
  if (tid < 128) {
    float s = conv_b[tid];
    for (int c = 0; c < 128; c++) s += conv_w[tid * 128 + c] * dS[c];
    biasp[b * 128 + tid] = s;
  }
}

// ---------------- K6: MFMA conv GEMM on bf16 y -> zpre + BN partial sums (R13 flow) ----
__launch_bounds__(256)
__global__ void k_conv(const short* __restrict__ Ybf, const short* __restrict__ Wpb,
                       const float* __restrict__ biasp, float* __restrict__ zpre,
                       float* __restrict__ bnSum, float* __restrict__ bnSq) {
  const int tid = threadIdx.x;
  const int wave = tid >> 6, lane = tid & 63;
  const int quad = lane >> 4, m = lane & 15;
  const int n0 = blockIdx.x * 64, b = blockIdx.z;
  const int obase = blockIdx.y * 64 + wave * 16;
  const short* arow = Wpb + (size_t)b * 16384 + (size_t)(obase + m) * 128;
  float4 bias = *(const float4*)&biasp[b * 128 + obase + quad * 4];
  f32x4 acc[4];
  #pragma unroll
  for (int pt = 0; pt < 4; pt++) { acc[pt][0] = bias.x; acc[pt][1] = bias.y; acc[pt][2] = bias.z; acc[pt][3] = bias.w; }
  #pragma unroll
  for (int ks = 0; ks < 4; ks++) {
    bf16x8 a = *(const bf16x8*)(arow + (ks * 4 + quad) * 8);
    #pragma unroll
    for (int pt = 0; pt < 4; pt++) {
      int n = n0 + pt * 16 + m;
      bf16x8 bfr = *(const bf16x8*)(Ybf + ((size_t)((b << 12) + n)) * 128 + (ks * 4 + quad) * 8);
      acc[pt] = __builtin_amdgcn_mfma_f32_16x16x32_bf16(a, bfr, acc[pt], 0, 0, 0);
    }
  }
  float p1[4] = {0.f, 0.f, 0.f, 0.f}, p2[4] = {0.f, 0.f, 0.f, 0.f};
  #pragma unroll
  for (int pt = 0; pt < 4; pt++) {
    int n = n0 + pt * 16 + m;
    #pragma unroll
    for (int r = 0; r < 4; r++) {
      float z = acc[pt][r];
      zpre[(((size_t)((b << 7) + obase + quad * 4 + r)) << 12) + n] = z;
      p1[r] += z; p2[r] += z * z;
    }
  }
  #pragma unroll
  for (int r = 0; r < 4; r++) {
    #pragma unroll
    for (int d = 1; d <= 8; d <<= 1) { p1[r] += __shfl_xor(p1[r], d); p2[r] += __shfl_xor(p2[r], d); }
  }
  if (m == 0) {
    #pragma unroll
    for (int r = 0; r < 4; r++) {
      atomicAdd(&bnSum[obase + quad * 4 + r], p1[r]);
      atomicAdd(&bnSq[obase + quad * 4 + r], p2[r]);
    }
  }
}

// ---------------- K7a: BN finalize ----------------
__global__ void k_bnfin(const float* __restrict__ bnSum, const float* __restrict__ bnSq,
                        const float* __restrict__ bn_g, const float* __restrict__ bn_b,
                        float* __restrict__ bnScale, float* __restrict__ bnShift) {
  int o = threadIdx.x;
  float m = bnSum[o] * (1.f / 16384.f);
  float v = bnSq[o] * (1.f / 16384.f) - m * m;
  float sc = bn_g[o] / sqrtf(v + 1e-5f);
  bnScale[o] = sc;
  bnShift[o] = bn_b[o] - m * sc;
}

// ---------------- K7b: normalize + ReLU -> d_out (R13 flow) ----------------
__global__ void k_final(const float* __restrict__ zpre, const float* __restrict__ bnScale,
                        const float* __restrict__ bnShift, float* __restrict__ out) {
  int i4 = blockIdx.x * 256 + threadIdx.x;
  int e = i4 * 4;
  int o = (e >> 12) & 127;
  float4 z = *(const float4*)&zpre[e];
  float sc = bnScale[o], sh = bnShift[o];
  float4 r;
  r.x = fmaxf(fmaf(z.x, sc, sh), 0.f);
  r.y = fmaxf(fmaf(z.y, sc, sh), 0.f);
  r.z = fmaxf(fmaf(z.z, sc, sh), 0.f);
  r.w = fmaxf(fmaf(z.w, sc, sh), 0.f);
  *(float4*)&out[e] = r;
}

extern "C" void kernel_launch(void* const* d_in, const int* in_sizes, int n_in,
                              void* d_out, int out_size, void* d_ws, size_t ws_size,
                              hipStream_t stream) {
  const float* features = (const float*)d_in[0];
  const float* w_lin  = (const float*)d_in[1];
  const float* b_lin  = (const float*)d_in[2];
  const float* w_aw   = (const float*)d_in[3];
  const float* b_aw   = (const float*)d_in[4];
  const float* gn_g   = (const float*)d_in[5];
  const float* gn_b   = (const float*)d_in[6];
  const float* conv_w = (const float*)d_in[7];
  const float* conv_b = (const float*)d_in[8];
  const float* bn_g   = (const float*)d_in[9];
  const float* bn_b   = (const float*)d_in[10];

  float* ws    = (float*)d_ws;
  float* xt    = ws + OFF_XT;
  float* xxp   = ws + OFF_XX;
  __hip_bfloat16* xhip = (__hip_bfloat16*)(ws + OFF_XHI);
  int*   idxp  = (int*)(ws + OFF_IDX);
  float* Op    = ws + OFF_O;
  float* candp = ws + OFF_O;   // alias: cand (2.1M floats) dead before k_linear writes O
  __hip_bfloat16* Ybf = (__hip_bfloat16*)(ws + OFF_Y);
  float* gnp   = ws + OFF_GNP;
  float* gnA   = ws + OFF_GNA;
  float* gnD   = ws + OFF_GND;
  float* biasp = ws + OFF_BIASP;
  float* bnSum = ws + OFF_BNSUM;
  float* bnSq  = ws + OFF_BNSQ;
  float* bnSc  = ws + OFF_BNSC;
  float* bnSh  = ws + OFF_BNSH;
  unsigned short* wlbp = (unsigned short*)(ws + OFF_WLB);
  float* biasB = ws + OFF_B320;
  unsigned short* wpbp = (unsigned short*)(ws + OFF_WPB);
  float* zpre  = xt; // alias: xt dead after k_attn

  hipMemsetAsync(xxp, 0, NPTS * BB * sizeof(float), stream);
  hipMemsetAsync(bnSum, 0, 256 * sizeof(float), stream); // bnSum + bnSq contiguous

  k_transpose<<<dim3(128, 4, 4), dim3(32, 32), 0, stream>>>(features, xt, xhip, xxp);
  k_wlinprep<<<160, 256, 0, stream>>>(w_lin, b_lin, w_aw, b_aw, wlbp, biasB);
  k_knn<<<dim3(128, 4, 2), 256, 0, stream>>>((const short*)xhip, xxp, candp);
  k_rerank<<<4096, 256, 0, stream>>>(candp, xt, xxp, idxp);
  k_linear<<<dim3(256, 5), 256, 0, stream>>>((const short*)xhip, (const short*)wlbp, biasB, Op);
  k_attn<<<4096, 256, 0, stream>>>(Op, idxp, xt, Ybf, gnp);
  k_gnstats<<<16, 256, 0, stream>>>(gnp, gn_g, gn_b, gnA, gnD);
  k_fold<<<4, 256, 0, stream>>>(conv_w, conv_b, gnA, gnD, wpbp, biasp);
  k_conv<<<dim3(64, 2, 4), 256, 0, stream>>>((const short*)Ybf, (const short*)wpbp, biasp,
                                             zpre, bnSum, bnSq);
  k_bnfin<<<1, 128, 0, stream>>>(bnSum, bnSq, bn_g, bn_b, bnSc, bnSh);
  k_final<<<2048, 256, 0, stream>>>(zpre, bnSc, bnSh, (float*)d_out);
}